// Round 3
// baseline (1243.652 us; speedup 1.0000x reference)
//
#include <hip/hip_runtime.h>
#include <hip/hip_bf16.h>

#define V     49152
#define NNZ   442368
#define EPS   1e-5f
#define VOUT  12288
#define SCP   260   // padded LDS row stride for transposed cheb tile

// ---------------- row_ptr via binary search + zero stats ----------------
__global__ __launch_bounds__(256) void k_rowptr(const int* __restrict__ rows,
                                                int* __restrict__ rp,
                                                float* __restrict__ stats) {
    int r = blockIdx.x * blockDim.x + threadIdx.x;
    if (r <= V) {
        int lo = 0, hi = NNZ;
        while (lo < hi) {
            int m = (lo + hi) >> 1;
            if (rows[m] < r) lo = m + 1; else hi = m;
        }
        rp[r] = lo;
    }
    if (blockIdx.x == 0 && threadIdx.x < 256) stats[threadIdx.x] = 0.f;
}

// ---------------- X1 = L @ X0 ----------------
__global__ __launch_bounds__(256) void k_spmm1(const float* __restrict__ x,
                                               const int* __restrict__ cols,
                                               const float* __restrict__ vals,
                                               const int* __restrict__ rp,
                                               float* __restrict__ X1) {
    int v = blockIdx.x, t = threadIdx.x;
    int s = rp[v], e = rp[v + 1];
    int i0 = t & 31, b0 = t >> 5;
    float a0 = 0.f, a1 = 0.f;
    for (int n = s; n < e; ++n) {
        int c = cols[n];
        float w = vals[n];
        a0 = fmaf(w, x[(size_t)(b0 * V + c) * 32 + i0], a0);
        a1 = fmaf(w, x[(size_t)((b0 + 8) * V + c) * 32 + i0], a1);
    }
    X1[(size_t)v * 512 + t]       = a0;
    X1[(size_t)v * 512 + t + 256] = a1;
}

// ---------------- X2 = 2 L @ X1 - X0 ----------------
__global__ __launch_bounds__(256) void k_spmm2(const float* __restrict__ x,
                                               const int* __restrict__ cols,
                                               const float* __restrict__ vals,
                                               const int* __restrict__ rp,
                                               const float* __restrict__ X1,
                                               float* __restrict__ X2) {
    int v = blockIdx.x, t = threadIdx.x;
    int s = rp[v], e = rp[v + 1];
    int i0 = t & 31, b0 = t >> 5;
    float a0 = 0.f, a1 = 0.f;
    for (int n = s; n < e; ++n) {
        int c = cols[n];
        float w = vals[n];
        a0 = fmaf(w, X1[(size_t)c * 512 + t], a0);
        a1 = fmaf(w, X1[(size_t)c * 512 + t + 256], a1);
    }
    X2[(size_t)v * 512 + t]       = 2.f * a0 - x[(size_t)(b0 * V + v) * 32 + i0];
    X2[(size_t)v * 512 + t + 256] = 2.f * a1 - x[(size_t)((b0 + 8) * V + v) * 32 + i0];
}

// ---- fused: X3 = 2 L @ X2 - X1 (regs only) + einsum over k=0..3 + BN stats + bf16 y ----
__global__ __launch_bounds__(256, 3) void k_cheb_out(const float* __restrict__ x,
                                                     const float* __restrict__ X1,
                                                     const float* __restrict__ X2,
                                                     const float* __restrict__ W,
                                                     const int* __restrict__ cols,
                                                     const float* __restrict__ vals,
                                                     const int* __restrict__ rp,
                                                     unsigned short* __restrict__ Y,
                                                     float* __restrict__ stats) {
    __shared__ float sW[2048];        // 8 KB, W_k as [i][o]
    __shared__ float sC[32 * SCP];    // 33.3 KB, cheb_k transposed: sC[i*SCP + r]
    __shared__ float lsum[64], lsq[64];

    int t = threadIdx.x;
    int v0 = blockIdx.x * 16;
    int i0 = t & 31, b0 = t >> 5;

    // phase0: gather X3 rows for 16 vertices, kept in registers
    float x3a[16], x3b[16];
#pragma unroll
    for (int vv = 0; vv < 16; ++vv) {
        int v = v0 + vv;
        int s = rp[v], e = rp[v + 1];
        float a0 = 0.f, a1 = 0.f;
        for (int n = s; n < e; ++n) {
            int c = cols[n];
            float w = vals[n];
            a0 = fmaf(w, X2[(size_t)c * 512 + t], a0);
            a1 = fmaf(w, X2[(size_t)c * 512 + t + 256], a1);
        }
        x3a[vv] = 2.f * a0 - X1[(size_t)v * 512 + t];
        x3b[vv] = 2.f * a1 - X1[(size_t)v * 512 + t + 256];
    }

    if (t < 64) { lsum[t] = 0.f; lsq[t] = 0.f; }

    int to = t & 7, tr = t >> 3;
    int r0 = tr * 8, o0 = to * 8;
    float acc[8][8];
#pragma unroll
    for (int j = 0; j < 8; ++j)
#pragma unroll
        for (int l = 0; l < 8; ++l) acc[j][l] = 0.f;

    // k-terms in order 3,0,1,2 (k=3 first frees the 32 X3 registers early)
#pragma unroll
    for (int kk = 0; kk < 4; ++kk) {
        const int k = (kk == 0) ? 3 : (kk - 1);
        __syncthreads();
        // stage W_k
        for (int j = t; j < 512; j += 256)
            *(float4*)&sW[j * 4] = *(const float4*)&W[k * 2048 + j * 4];
        // stage cheb_k tile, transposed into sC[i][r], r = vv*16 + b
        if (k == 3) {
#pragma unroll
            for (int vv = 0; vv < 16; ++vv) {
                sC[i0 * SCP + vv * 16 + b0]     = x3a[vv];
                sC[i0 * SCP + vv * 16 + b0 + 8] = x3b[vv];
            }
        } else {
            for (int j = t; j < 2048; j += 256) {
                int r = j >> 3, i4 = j & 7;
                int vv = r >> 4, b = r & 15;
                int v = v0 + vv;
                float4 val;
                if (k == 0)      val = *(const float4*)&x[(size_t)(b * V + v) * 32 + i4 * 4];
                else if (k == 1) val = *(const float4*)&X1[(size_t)v * 512 + b * 32 + i4 * 4];
                else             val = *(const float4*)&X2[(size_t)v * 512 + b * 32 + i4 * 4];
                int ib = i4 * 4;
                sC[(ib + 0) * SCP + r] = val.x;
                sC[(ib + 1) * SCP + r] = val.y;
                sC[(ib + 2) * SCP + r] = val.z;
                sC[(ib + 3) * SCP + r] = val.w;
            }
        }
        __syncthreads();
#pragma unroll
        for (int i = 0; i < 32; ++i) {
            float4 ca = *(const float4*)&sC[i * SCP + r0];
            float4 cb = *(const float4*)&sC[i * SCP + r0 + 4];
            float4 wa = *(const float4*)&sW[i * 64 + o0];
            float4 wb = *(const float4*)&sW[i * 64 + o0 + 4];
            float c[8] = {ca.x, ca.y, ca.z, ca.w, cb.x, cb.y, cb.z, cb.w};
            float w[8] = {wa.x, wa.y, wa.z, wa.w, wb.x, wb.y, wb.z, wb.w};
#pragma unroll
            for (int j = 0; j < 8; ++j)
#pragma unroll
                for (int l = 0; l < 8; ++l)
                    acc[j][l] = fmaf(c[j], w[l], acc[j][l]);
        }
    }

    // y write (bf16) — layout Y[v][b][o]
#pragma unroll
    for (int j = 0; j < 8; ++j) {
        int r = r0 + j;
        int vv = r >> 4, b = r & 15;
        union { unsigned short u[8]; uint4 q; } p;
#pragma unroll
        for (int l = 0; l < 8; ++l) {
            __hip_bfloat16 h = __float2bfloat16(acc[j][l]);
            p.u[l] = *reinterpret_cast<unsigned short*>(&h);
        }
        *(uint4*)&Y[(size_t)(v0 + vv) * 1024 + b * 64 + o0] = p.q;
    }

    // BN partial sums (exact fp32 accumulators)
#pragma unroll
    for (int l = 0; l < 8; ++l) {
        float s = 0.f, q = 0.f;
#pragma unroll
        for (int j = 0; j < 8; ++j) { float a = acc[j][l]; s += a; q = fmaf(a, a, q); }
        atomicAdd(&lsum[o0 + l], s);
        atomicAdd(&lsq[o0 + l], q);
    }
    __syncthreads();
    if (t < 64) {
        atomicAdd(&stats[t], lsum[t]);
        atomicAdd(&stats[64 + t], lsq[t]);
    }
}

// ---------------- finalize BN scale/shift ----------------
__global__ void k_bnfin(const float* __restrict__ gamma, const float* __restrict__ beta,
                        float* __restrict__ stats) {
    int o = threadIdx.x;
    if (o < 64) {
        float n = (float)(16 * V);
        float mean = stats[o] / n;
        float var = stats[64 + o] / n - mean * mean;
        float sc = gamma[o] * rsqrtf(var + EPS);
        stats[128 + o] = sc;
        stats[192 + o] = beta[o] - mean * sc;
    }
}

// ---------------- BN apply + ReLU + pool(4), bf16 y in ----------------
__global__ __launch_bounds__(256) void k_pool(const unsigned short* __restrict__ Y,
                                              const float* __restrict__ stats,
                                              float* __restrict__ out) {
    int id = blockIdx.x * blockDim.x + threadIdx.x;
    int o4 = id & 15;
    int b  = (id >> 4) & 15;
    int vp = id >> 8;
    float4 sc = *(const float4*)&stats[128 + o4 * 4];
    float4 sh = *(const float4*)&stats[192 + o4 * 4];
    float ax = 0.f, ay = 0.f, az = 0.f, aw = 0.f;
#pragma unroll
    for (int j = 0; j < 4; ++j) {
        ushort4 u = *(const ushort4*)&Y[(size_t)((vp * 4 + j) * 16 + b) * 64 + o4 * 4];
        float tx = __uint_as_float((unsigned)u.x << 16);
        float ty = __uint_as_float((unsigned)u.y << 16);
        float tz = __uint_as_float((unsigned)u.z << 16);
        float tw = __uint_as_float((unsigned)u.w << 16);
        ax += fmaxf(fmaf(tx, sc.x, sh.x), 0.f);
        ay += fmaxf(fmaf(ty, sc.y, sh.y), 0.f);
        az += fmaxf(fmaf(tz, sc.z, sh.z), 0.f);
        aw += fmaxf(fmaf(tw, sc.w, sh.w), 0.f);
    }
    float4 res = {ax * 0.25f, ay * 0.25f, az * 0.25f, aw * 0.25f};
    *(float4*)&out[(size_t)((b * VOUT + vp) * 16 + o4) * 4] = res;
}

extern "C" void kernel_launch(void* const* d_in, const int* in_sizes, int n_in,
                              void* d_out, int out_size, void* d_ws, size_t ws_size,
                              hipStream_t stream) {
    const float* x     = (const float*)d_in[0];
    const float* vals  = (const float*)d_in[1];
    const float* W     = (const float*)d_in[2];
    const float* gamma = (const float*)d_in[3];
    const float* beta  = (const float*)d_in[4];
    const int*   rows  = (const int*)d_in[5];
    const int*   cols  = (const int*)d_in[6];
    float* out = (float*)d_out;

    char* ws = (char*)d_ws;
    float* X1 = (float*)ws;                               // 100,663,296 B
    float* X2 = (float*)(ws + 100663296UL);               // 100,663,296 B
    unsigned short* Y = (unsigned short*)(ws + 201326592UL); // 100,663,296 B (bf16 [v][b][o])
    int*   rp    = (int*)(ws + 301989888UL);              // 196,612 B
    float* stats = (float*)(ws + 301989888UL + 197120UL); // 1 KB

    k_rowptr<<<193, 256, 0, stream>>>(rows, rp, stats);
    k_spmm1<<<V, 256, 0, stream>>>(x, cols, vals, rp, X1);
    k_spmm2<<<V, 256, 0, stream>>>(x, cols, vals, rp, X1, X2);
    k_cheb_out<<<V / 16, 256, 0, stream>>>(x, X1, X2, W, cols, vals, rp, Y, stats);
    k_bnfin<<<1, 64, 0, stream>>>(gamma, beta, stats);
    k_pool<<<12288, 256, 0, stream>>>(Y, stats, out);
}